// Round 6
// baseline (59.587 us; speedup 1.0000x reference)
//
#include <hip/hip_runtime.h>
#include <math.h>

#define SF 0.99999f
#define PI2 6.283185307179586476925f
#define SWZ(c) ((c) ^ (((c) >> 4) & 15))
// compiler-only fence: orders same-wave LDS write/read phases (HW LDS pipe is
// in-order per wave; this stops compiler reordering).
#define LDSFENCE() asm volatile("" ::: "memory")

template<int SGN>
__device__ __forceinline__ void twmul(float& ur, float& ui, float c, float s) {
    const float ss = (SGN < 0) ? -s : s;
    const float r = ur * c - ui * ss;
    const float i = ui * c + ur * ss;
    ur = r; ui = i;
}

// 8-point DFT across registers. SGN=-1: forward; SGN=+1: inverse.
template<int SGN>
__device__ __forceinline__ void bfly8(float* ur, float* ui) {
    const float C2 = 0.70710678118654752440f;
    float ar[4], ai[4], br[4], bi[4];
#pragma unroll
    for (int m = 0; m < 4; ++m) {
        ar[m] = ur[m] + ur[m + 4]; ai[m] = ui[m] + ui[m + 4];
        br[m] = ur[m] - ur[m + 4]; bi[m] = ui[m] - ui[m + 4];
    }
    float b1r, b1i, b2r, b2i, b3r, b3i;
    if (SGN < 0) {
        b1r = C2 * (br[1] + bi[1]); b1i = C2 * (bi[1] - br[1]);
        b2r = bi[2];                b2i = -br[2];
        b3r = C2 * (bi[3] - br[3]); b3i = -C2 * (br[3] + bi[3]);
    } else {
        b1r = C2 * (br[1] - bi[1]); b1i = C2 * (bi[1] + br[1]);
        b2r = -bi[2];               b2i = br[2];
        b3r = -C2 * (br[3] + bi[3]); b3i = C2 * (br[3] - bi[3]);
    }
    const float e0r = ar[0] + ar[2], e0i = ai[0] + ai[2];
    const float e1r = ar[0] - ar[2], e1i = ai[0] - ai[2];
    const float o0r = ar[1] + ar[3], o0i = ai[1] + ai[3];
    const float o1r = ar[1] - ar[3], o1i = ai[1] - ai[3];
    ur[0] = e0r + o0r; ui[0] = e0i + o0i;
    ur[4] = e0r - o0r; ui[4] = e0i - o0i;
    if (SGN < 0) { ur[2] = e1r + o1i; ui[2] = e1i - o1r; ur[6] = e1r - o1i; ui[6] = e1i + o1r; }
    else         { ur[2] = e1r - o1i; ui[2] = e1i + o1r; ur[6] = e1r + o1i; ui[6] = e1i - o1r; }
    const float f0r = br[0] + b2r, f0i = bi[0] + b2i;
    const float f1r = br[0] - b2r, f1i = bi[0] - b2i;
    const float g0r = b1r + b3r, g0i = b1i + b3i;
    const float g1r = b1r - b3r, g1i = b1i - b3i;
    ur[1] = f0r + g0r; ui[1] = f0i + g0i;
    ur[5] = f0r - g0r; ui[5] = f0i - g0i;
    if (SGN < 0) { ur[3] = f1r + g1i; ui[3] = f1i - g1r; ur[7] = f1r - g1i; ui[7] = f1i + g1r; }
    else         { ur[3] = f1r - g1i; ui[3] = f1i + g1r; ur[7] = f1r + g1i; ui[7] = f1i - g1r; }
}

// Wave-local 512-pt complex FFT, Stockham radix-8, 3 stages, single LDS buffer.
// slot m of lane t <-> element (t + 64*m), natural order both sides. No barriers.
template<int SGN>
__device__ __forceinline__ void fft512w(float* ur, float* ui,
                                        float2* __restrict__ buf,
                                        const float2* __restrict__ tw2,
                                        const float2* __restrict__ tw3,
                                        int t) {
    bfly8<SGN>(ur, ui);
    LDSFENCE();
#pragma unroll
    for (int m = 0; m < 8; ++m) buf[SWZ(8 * t + m)] = make_float2(ur[m], ui[m]);
    LDSFENCE();
#pragma unroll
    for (int m = 0; m < 8; ++m) { const float2 v = buf[SWZ(t + 64 * m)]; ur[m] = v.x; ui[m] = v.y; }
    const int k2 = t & 7;
#pragma unroll
    for (int m = 1; m < 8; ++m) { const float2 w = tw2[m * 8 + k2]; twmul<SGN>(ur[m], ui[m], w.x, w.y); }
    bfly8<SGN>(ur, ui);
    const int jj = ((t >> 3) << 6) + k2;
    LDSFENCE();
#pragma unroll
    for (int m = 0; m < 8; ++m) buf[SWZ(jj + 8 * m)] = make_float2(ur[m], ui[m]);
    LDSFENCE();
#pragma unroll
    for (int m = 0; m < 8; ++m) { const float2 v = buf[SWZ(t + 64 * m)]; ur[m] = v.x; ui[m] = v.y; }
#pragma unroll
    for (int m = 1; m < 8; ++m) { const float2 w = tw3[m * 64 + t]; twmul<SGN>(ur[m], ui[m], w.x, w.y); }
    bfly8<SGN>(ur, ui);
    LDSFENCE();
}

// Two independent 512-pt FFTs interleaved: shared latency windows, 2x VALU per
// LDS stall, half the serial stall windows of two sequential calls.
template<int SGN>
__device__ __forceinline__ void fft512w_dual(float* urA, float* uiA,
                                             float* urB, float* uiB,
                                             float2* __restrict__ bufA,
                                             float2* __restrict__ bufB,
                                             const float2* __restrict__ tw2,
                                             const float2* __restrict__ tw3,
                                             int t) {
    bfly8<SGN>(urA, uiA);
    bfly8<SGN>(urB, uiB);
    LDSFENCE();
#pragma unroll
    for (int m = 0; m < 8; ++m) bufA[SWZ(8 * t + m)] = make_float2(urA[m], uiA[m]);
#pragma unroll
    for (int m = 0; m < 8; ++m) bufB[SWZ(8 * t + m)] = make_float2(urB[m], uiB[m]);
    LDSFENCE();
#pragma unroll
    for (int m = 0; m < 8; ++m) { const float2 v = bufA[SWZ(t + 64 * m)]; urA[m] = v.x; uiA[m] = v.y; }
#pragma unroll
    for (int m = 0; m < 8; ++m) { const float2 v = bufB[SWZ(t + 64 * m)]; urB[m] = v.x; uiB[m] = v.y; }
    const int k2 = t & 7;
#pragma unroll
    for (int m = 1; m < 8; ++m) {
        const float2 wv = tw2[m * 8 + k2];
        twmul<SGN>(urA[m], uiA[m], wv.x, wv.y);
        twmul<SGN>(urB[m], uiB[m], wv.x, wv.y);
    }
    bfly8<SGN>(urA, uiA);
    bfly8<SGN>(urB, uiB);
    const int jj = ((t >> 3) << 6) + k2;
    LDSFENCE();
#pragma unroll
    for (int m = 0; m < 8; ++m) bufA[SWZ(jj + 8 * m)] = make_float2(urA[m], uiA[m]);
#pragma unroll
    for (int m = 0; m < 8; ++m) bufB[SWZ(jj + 8 * m)] = make_float2(urB[m], uiB[m]);
    LDSFENCE();
#pragma unroll
    for (int m = 0; m < 8; ++m) { const float2 v = bufA[SWZ(t + 64 * m)]; urA[m] = v.x; uiA[m] = v.y; }
#pragma unroll
    for (int m = 0; m < 8; ++m) { const float2 v = bufB[SWZ(t + 64 * m)]; urB[m] = v.x; uiB[m] = v.y; }
#pragma unroll
    for (int m = 1; m < 8; ++m) {
        const float2 wv = tw3[m * 64 + t];
        twmul<SGN>(urA[m], uiA[m], wv.x, wv.y);
        twmul<SGN>(urB[m], uiB[m], wv.x, wv.y);
    }
    bfly8<SGN>(urA, uiA);
    bfly8<SGN>(urB, uiB);
    LDSFENCE();
}

__global__ __launch_bounds__(256, 3) void pbfd_kernel(
    const float* __restrict__ g_mic,   // (B,256)
    const float* __restrict__ g_lsb,   // (B,1280)
    const float* __restrict__ g_phie,  // (B,257)
    const float* __restrict__ g_p1,    // (B,257,4)
    const float* __restrict__ g_hr,    // (B,257,4)
    const float* __restrict__ g_hi,    // (B,257,4)
    float* __restrict__ g_out,         // (B,256)
    int B) {
    __shared__ float2 tw2[64];
    __shared__ float2 tw3[512];
    __shared__ float2 xch[4][2][512];  // two exchange buffers per wave (dual FFT)
    __shared__ float nyq[4][14];       // per-wave lane-0 side channel:
                                       // [0..3]=xn [4..7]=hn [8..11]=pn [12]=phie256/pen [13]=en

    const int tid = threadIdx.x;
    const int w = tid >> 6;
    const int t = tid & 63;
    const int elem = blockIdx.x * 4 + w;
    const int ec = (elem < B) ? elem : (B - 1);  // clamp loads; stores guarded below
    const int ml = (64 - t) & 63;  // mirror lane: bin 512-k lives at (ml, 7-m) for t>=1

    // ---- prefetch inputs (consumption order; latency covered by table sincos) ----
    float u[20];  // lsb: frames overlap, 20 unique stride-64 values/lane
    {
        const float* lb = g_lsb + (size_t)ec * 1280;
#pragma unroll
        for (int m = 0; m < 20; ++m) u[m] = lb[t + 64 * m];
    }
    float mv[4];
    {
        const float* mp = g_mic + (size_t)ec * 256;
#pragma unroll
        for (int q = 0; q < 4; ++q) mv[q] = mp[t + 64 * q];
    }
    float hr_[4][4], hi_[4][4];
    {
        const float4* hr4 = (const float4*)g_hr + (size_t)ec * 257;
        const float4* hi4 = (const float4*)g_hi + (size_t)ec * 257;
#pragma unroll
        for (int m = 0; m < 4; ++m) {
            const float4 a = hr4[t + 64 * m];
            hr_[0][m] = a.x; hr_[1][m] = a.y; hr_[2][m] = a.z; hr_[3][m] = a.w;
        }
#pragma unroll
        for (int m = 0; m < 4; ++m) {
            const float4 b = hi4[t + 64 * m];
            hi_[0][m] = b.x; hi_[1][m] = b.y; hi_[2][m] = b.z; hi_[3][m] = b.w;
        }
    }
    float phv[4];
    {
        const float* php = g_phie + (size_t)ec * 257;
#pragma unroll
        for (int m = 0; m < 4; ++m) phv[m] = php[t + 64 * m];
    }
    float4 p1q[4];
    {
        const float4* p14 = (const float4*)g_p1 + (size_t)ec * 257;
#pragma unroll
        for (int m = 0; m < 4; ++m) p1q[m] = p14[t + 64 * m];
    }
    float4 hnl = make_float4(0.f, 0.f, 0.f, 0.f), pnl = make_float4(0.f, 0.f, 0.f, 0.f);
    float ph256 = 0.f;
    if (t == 0) {
        hnl = ((const float4*)g_hr)[(size_t)ec * 257 + 256];
        pnl = ((const float4*)g_p1)[(size_t)ec * 257 + 256];
        ph256 = g_phie[(size_t)ec * 257 + 256];
    }

    // ---- twiddle tables ----
    for (int e = tid; e < 512; e += 256) {
        const int m = e >> 6, tt = e & 63;
        float s, c;
        sincosf(PI2 * (float)(m * tt) * (1.0f / 512.0f), &s, &c);
        tw3[e] = make_float2(c, s);
    }
    if (tid < 64) {
        const int m = tid >> 3, k = tid & 7;
        float s, c;
        sincosf(PI2 * (float)(m * k) * (1.0f / 64.0f), &s, &c);
        tw2[tid] = make_float2(c, s);
    }
    __syncthreads();  // the only barrier

    float2* bufA = &xch[w][0][0];
    float2* bufB = &xch[w][1][0];
    float* ny = &nyq[w][0];
    if (t == 0) {
        ny[4] = hnl.x; ny[5] = hnl.y; ny[6] = hnl.z; ny[7] = hnl.w;
        ny[8] = pnl.x; ny[9] = pnl.y; ny[10] = pnl.z; ny[11] = pnl.w;
        ny[12] = ph256;
    }
    LDSFENCE();

    // ---- de-phase waves/blocks so LDS exchange bursts decorrelate ----
    switch ((w + ((blockIdx.x & 1) << 2)) & 7) {
        case 1: __builtin_amdgcn_s_sleep(2); break;
        case 2: __builtin_amdgcn_s_sleep(4); break;
        case 3: __builtin_amdgcn_s_sleep(6); break;
        case 4: __builtin_amdgcn_s_sleep(8); break;
        case 5: __builtin_amdgcn_s_sleep(10); break;
        case 6: __builtin_amdgcn_s_sleep(12); break;
        case 7: __builtin_amdgcn_s_sleep(14); break;
        default: break;
    }

    // ---- X: 4 real frame-FFTs as one DUAL complex FFT ----
    float xr[4][4], xi[4][4];
    {
        float urA[8], uiA[8], urB[8], uiB[8];
#pragma unroll
        for (int m = 0; m < 8; ++m) {
            urA[m] = u[m];     uiA[m] = u[m + 4];    // frames 0,1
            urB[m] = u[m + 8]; uiB[m] = u[m + 12];   // frames 2,3
        }
        fft512w_dual<-1>(urA, uiA, urB, uiB, bufA, bufB, tw2, tw3, t);
        // unpack low bins (Hermitian split of the packed pair)
#pragma unroll
        for (int m = 0; m < 4; ++m) {
            float zmr = __shfl(urA[7 - m], ml);
            float zmi = __shfl(uiA[7 - m], ml);
            if (t == 0) { zmr = (m == 0) ? urA[0] : urA[8 - m]; zmi = (m == 0) ? uiA[0] : uiA[8 - m]; }
            xr[0][m] = 0.5f * (urA[m] + zmr);
            xi[0][m] = 0.5f * (uiA[m] - zmi);
            xr[1][m] = 0.5f * (uiA[m] + zmi);
            xi[1][m] = -0.5f * (urA[m] - zmr);
        }
#pragma unroll
        for (int m = 0; m < 4; ++m) {
            float zmr = __shfl(urB[7 - m], ml);
            float zmi = __shfl(uiB[7 - m], ml);
            if (t == 0) { zmr = (m == 0) ? urB[0] : urB[8 - m]; zmi = (m == 0) ? uiB[0] : uiB[8 - m]; }
            xr[2][m] = 0.5f * (urB[m] + zmr);
            xi[2][m] = 0.5f * (uiB[m] - zmi);
            xr[3][m] = 0.5f * (uiB[m] + zmi);
            xi[3][m] = -0.5f * (urB[m] - zmr);
        }
        if (t == 0) { ny[0] = urA[4]; ny[1] = uiA[4]; ny[2] = urB[4]; ny[3] = uiB[4]; }
        LDSFENCE();
    }

    // C = sum_j X*H at low slots; Hermitian high-half reconstruction; IFFT; o4 = Re(out)[4..7]/512
    auto sum_ifft = [&](float o4[4]) {
        float ur[8], ui[8];
#pragma unroll
        for (int m = 0; m < 4; ++m) {
            float cr = 0.f, ci = 0.f;
#pragma unroll
            for (int j = 0; j < 4; ++j) {
                cr += xr[j][m] * hr_[j][m] - xi[j][m] * hi_[j][m];
                ci += xr[j][m] * hi_[j][m] + xi[j][m] * hr_[j][m];
            }
            ur[m] = cr; ui[m] = ci;
        }
#pragma unroll
        for (int m = 4; m < 8; ++m) {  // high slot = conj(mirror-lane low slot 7-m)
            const float cr = __shfl(ur[7 - m], ml);
            const float ci = __shfl(ui[7 - m], ml);
            ur[m] = cr; ui[m] = -ci;
        }
        if (t == 0) {
            ur[5] = ur[3]; ui[5] = -ui[3];
            ur[6] = ur[2]; ui[6] = -ui[2];
            ur[7] = ur[1]; ui[7] = -ui[1];
            float cn = 0.f;
#pragma unroll
            for (int j = 0; j < 4; ++j) cn += ny[j] * ny[4 + j];
            ur[4] = cn; ui[4] = 0.f;  // Nyquist: real
        }
        fft512w<1>(ur, ui, bufA, tw2, tw3, t);
#pragma unroll
        for (int q = 0; q < 4; ++q) o4[q] = ur[4 + q] * (1.0f / 512.0f);
    };

    // ---- est (H prior), d = mic - est ----
    float d4[4];
    {
        float o4[4];
        sum_ifft(o4);
#pragma unroll
        for (int q = 0; q < 4; ++q) d4[q] = mv[q] - o4[q];
    }

    // ---- E = FFT([zeros(256); d]) ----
    float er[4], ei[4];
    {
        float ur[8], ui[8];
#pragma unroll
        for (int m = 0; m < 4; ++m) { ur[m] = 0.f; ui[m] = 0.f; }
#pragma unroll
        for (int q = 0; q < 4; ++q) { ur[4 + q] = d4[q]; ui[4 + q] = 0.f; }
        fft512w<-1>(ur, ui, bufA, tw2, tw3, t);
#pragma unroll
        for (int m = 0; m < 4; ++m) { er[m] = ur[m]; ei[m] = ui[m]; }
        if (t == 0) {
            const float en = ur[4];
            ny[13] = en;
            ny[12] = 0.7f * ny[12] + 0.3f * en * en;  // pen
        }
        LDSFENCE();
    }

    // ---- phi_e ----
    float pe[4];
#pragma unroll
    for (int m = 0; m < 4; ++m)
        pe[m] = 0.7f * phv[m] + 0.3f * (er[m] * er[m] + ei[m] * ei[m]);

    // ---- gradient: all 4 partitions in ONE dual pipeline:
    //      A = KE0 + i*KE1, B = KE2 + i*KE3; dual-IFFT -> mask -> dual-FFT -> unpack ----
    {
        float urA[8], uiA[8], urB[8], uiB[8];
        float grA[4], giA[4], grB[4], giB[4];
#pragma unroll
        for (int m = 0; m < 4; ++m) {
            // KE_j = P1_j * conj(X_j) / R_j * E
            const float xx0 = xr[0][m] * xr[0][m] + xi[0][m] * xi[0][m];
            const float R0 = xx0 * p1q[m].x + 2.f * pe[m] + 1e-10f;
            const float i0 = 1.f / R0;
            const float kr0 = p1q[m].x * xr[0][m] * i0, ki0 = -p1q[m].x * xi[0][m] * i0;
            const float a_r = kr0 * er[m] - ki0 * ei[m];
            const float a_i = kr0 * ei[m] + ki0 * er[m];
            const float xx1 = xr[1][m] * xr[1][m] + xi[1][m] * xi[1][m];
            const float R1 = xx1 * p1q[m].y + 2.f * pe[m] + 1e-10f;
            const float i1 = 1.f / R1;
            const float kr1 = p1q[m].y * xr[1][m] * i1, ki1 = -p1q[m].y * xi[1][m] * i1;
            const float b_r = kr1 * er[m] - ki1 * ei[m];
            const float b_i = kr1 * ei[m] + ki1 * er[m];
            urA[m] = a_r - b_i;  uiA[m] = a_i + b_r;   // KE0 + i*KE1
            grA[m] = a_r + b_i;  giA[m] = b_r - a_i;   // conj-pack for mirror lanes

            const float xx2 = xr[2][m] * xr[2][m] + xi[2][m] * xi[2][m];
            const float R2 = xx2 * p1q[m].z + 2.f * pe[m] + 1e-10f;
            const float i2 = 1.f / R2;
            const float kr2 = p1q[m].z * xr[2][m] * i2, ki2 = -p1q[m].z * xi[2][m] * i2;
            const float c_r = kr2 * er[m] - ki2 * ei[m];
            const float c_i = kr2 * ei[m] + ki2 * er[m];
            const float xx3 = xr[3][m] * xr[3][m] + xi[3][m] * xi[3][m];
            const float R3 = xx3 * p1q[m].w + 2.f * pe[m] + 1e-10f;
            const float i3 = 1.f / R3;
            const float kr3 = p1q[m].w * xr[3][m] * i3, ki3 = -p1q[m].w * xi[3][m] * i3;
            const float d_r = kr3 * er[m] - ki3 * ei[m];
            const float d_i = kr3 * ei[m] + ki3 * er[m];
            urB[m] = c_r - d_i;  uiB[m] = c_i + d_r;   // KE2 + i*KE3
            grB[m] = c_r + d_i;  giB[m] = d_r - c_i;
        }
#pragma unroll
        for (int m = 4; m < 8; ++m) {
            urA[m] = __shfl(grA[7 - m], ml);
            uiA[m] = __shfl(giA[7 - m], ml);
            urB[m] = __shfl(grB[7 - m], ml);
            uiB[m] = __shfl(giB[7 - m], ml);
        }
        if (t == 0) {
            urA[5] = grA[3]; uiA[5] = giA[3];
            urA[6] = grA[2]; uiA[6] = giA[2];
            urA[7] = grA[1]; uiA[7] = giA[1];
            urB[5] = grB[3]; uiB[5] = giB[3];
            urB[6] = grB[2]; uiB[6] = giB[2];
            urB[7] = grB[1]; uiB[7] = giB[1];
            const float en = ny[13], pen = ny[12];
#pragma unroll
            for (int j = 0; j < 4; ++j) {
                const float xnj = ny[j], pnj = ny[8 + j];
                const float Rn = xnj * xnj * pnj + 2.f * pen + 1e-10f;
                const float ke = pnj * xnj / Rn * en;  // KE_j[256] (real)
                if (j == 0) urA[4] = ke;
                else if (j == 1) uiA[4] = ke;
                else if (j == 2) urB[4] = ke;
                else uiB[4] = ke;
            }
        }
        fft512w_dual<1>(urA, uiA, urB, uiB, bufA, bufB, tw2, tw3, t);  // 512*(dH pairs)
        // mask n<256 (slots m<4), scale 1/512
#pragma unroll
        for (int m = 0; m < 4; ++m) {
            urA[m] *= (1.0f / 512.0f); uiA[m] *= (1.0f / 512.0f);
            urB[m] *= (1.0f / 512.0f); uiB[m] *= (1.0f / 512.0f);
        }
#pragma unroll
        for (int m = 4; m < 8; ++m) {
            urA[m] = 0.f; uiA[m] = 0.f;
            urB[m] = 0.f; uiB[m] = 0.f;
        }
        fft512w_dual<-1>(urA, uiA, urB, uiB, bufA, bufB, tw2, tw3, t);  // fd_dH pairs
        // unpack at low slots: fd0 = (Z + conj(Zm))/2, fd1 = -i/2 (Z - conj(Zm))
#pragma unroll
        for (int m = 0; m < 4; ++m) {
            float zmr = __shfl(urA[7 - m], ml);
            float zmi = __shfl(uiA[7 - m], ml);
            if (t == 0) { zmr = (m == 0) ? urA[0] : urA[8 - m]; zmi = (m == 0) ? uiA[0] : uiA[8 - m]; }
            hr_[0][m] = SF * (hr_[0][m] + 0.5f * (urA[m] + zmr));
            hi_[0][m] = SF * (hi_[0][m] + 0.5f * (uiA[m] - zmi));
            hr_[1][m] = SF * (hr_[1][m] + 0.5f * (uiA[m] + zmi));
            hi_[1][m] = SF * (hi_[1][m] - 0.5f * (urA[m] - zmr));
        }
#pragma unroll
        for (int m = 0; m < 4; ++m) {
            float zmr = __shfl(urB[7 - m], ml);
            float zmi = __shfl(uiB[7 - m], ml);
            if (t == 0) { zmr = (m == 0) ? urB[0] : urB[8 - m]; zmi = (m == 0) ? uiB[0] : uiB[8 - m]; }
            hr_[2][m] = SF * (hr_[2][m] + 0.5f * (urB[m] + zmr));
            hi_[2][m] = SF * (hi_[2][m] + 0.5f * (uiB[m] - zmi));
            hr_[3][m] = SF * (hr_[3][m] + 0.5f * (uiB[m] + zmi));
            hi_[3][m] = SF * (hi_[3][m] - 0.5f * (urB[m] - zmr));
        }
        if (t == 0) {
            ny[4] = SF * (ny[4] + urA[4]);  // fd_dH0[256] = Re(ZA4)
            ny[5] = SF * (ny[5] + uiA[4]);  // fd_dH1[256] = Im(ZA4)
            ny[6] = SF * (ny[6] + urB[4]);
            ny[7] = SF * (ny[7] + uiB[4]);
        }
        LDSFENCE();
    }

    // ---- enhanced = mic - Re(IFFT(sum X*H_new))[256:] ----
    {
        float o4[4];
        sum_ifft(o4);
        if (elem < B) {
            float* op = g_out + (size_t)elem * 256;
#pragma unroll
            for (int q = 0; q < 4; ++q) op[t + 64 * q] = mv[q] - o4[q];
        }
    }
}

extern "C" void kernel_launch(void* const* d_in, const int* in_sizes, int n_in,
                              void* d_out, int out_size, void* d_ws, size_t ws_size,
                              hipStream_t stream) {
    const float* mic  = (const float*)d_in[0];
    const float* lsb  = (const float*)d_in[1];
    const float* phie = (const float*)d_in[2];
    // d_in[3] = phi_f: dead for the 'enhanced' output
    const float* p1   = (const float*)d_in[4];
    const float* hr   = (const float*)d_in[5];
    const float* hi   = (const float*)d_in[6];
    float* out = (float*)d_out;

    const int B = in_sizes[0] / 256;  // N_MIC == 1
    const int blocks = (B + 3) / 4;   // 4 elements (waves) per 256-thread block
    pbfd_kernel<<<blocks, 256, 0, stream>>>(mic, lsb, phie, p1, hr, hi, out, B);
}

// Round 7
// 50.295 us; speedup vs baseline: 1.1847x; 1.1847x over previous
//
#include <hip/hip_runtime.h>
#include <math.h>

#define SF 0.99999f
#define PI2 6.283185307179586476925f
#define SWZ(c) ((c) ^ (((c) >> 4) & 15))
// compiler-only fence: orders same-wave LDS write/read phases (HW LDS pipe is
// in-order per wave; this stops compiler reordering).
#define LDSFENCE() asm volatile("" ::: "memory")

template<int SGN>
__device__ __forceinline__ void twmul(float& ur, float& ui, float c, float s) {
    const float ss = (SGN < 0) ? -s : s;
    const float r = ur * c - ui * ss;
    const float i = ui * c + ur * ss;
    ur = r; ui = i;
}

// 8-point DFT across registers. SGN=-1: forward; SGN=+1: inverse.
template<int SGN>
__device__ __forceinline__ void bfly8(float* ur, float* ui) {
    const float C2 = 0.70710678118654752440f;
    float ar[4], ai[4], br[4], bi[4];
#pragma unroll
    for (int m = 0; m < 4; ++m) {
        ar[m] = ur[m] + ur[m + 4]; ai[m] = ui[m] + ui[m + 4];
        br[m] = ur[m] - ur[m + 4]; bi[m] = ui[m] - ui[m + 4];
    }
    float b1r, b1i, b2r, b2i, b3r, b3i;
    if (SGN < 0) {
        b1r = C2 * (br[1] + bi[1]); b1i = C2 * (bi[1] - br[1]);
        b2r = bi[2];                b2i = -br[2];
        b3r = C2 * (bi[3] - br[3]); b3i = -C2 * (br[3] + bi[3]);
    } else {
        b1r = C2 * (br[1] - bi[1]); b1i = C2 * (bi[1] + br[1]);
        b2r = -bi[2];               b2i = br[2];
        b3r = -C2 * (br[3] + bi[3]); b3i = C2 * (br[3] - bi[3]);
    }
    const float e0r = ar[0] + ar[2], e0i = ai[0] + ai[2];
    const float e1r = ar[0] - ar[2], e1i = ai[0] - ai[2];
    const float o0r = ar[1] + ar[3], o0i = ai[1] + ai[3];
    const float o1r = ar[1] - ar[3], o1i = ai[1] - ai[3];
    ur[0] = e0r + o0r; ui[0] = e0i + o0i;
    ur[4] = e0r - o0r; ui[4] = e0i - o0i;
    if (SGN < 0) { ur[2] = e1r + o1i; ui[2] = e1i - o1r; ur[6] = e1r - o1i; ui[6] = e1i + o1r; }
    else         { ur[2] = e1r - o1i; ui[2] = e1i + o1r; ur[6] = e1r + o1i; ui[6] = e1i - o1r; }
    const float f0r = br[0] + b2r, f0i = bi[0] + b2i;
    const float f1r = br[0] - b2r, f1i = bi[0] - b2i;
    const float g0r = b1r + b3r, g0i = b1i + b3i;
    const float g1r = b1r - b3r, g1i = b1i - b3i;
    ur[1] = f0r + g0r; ui[1] = f0i + g0i;
    ur[5] = f0r - g0r; ui[5] = f0i - g0i;
    if (SGN < 0) { ur[3] = f1r + g1i; ui[3] = f1i - g1r; ur[7] = f1r - g1i; ui[7] = f1i + g1r; }
    else         { ur[3] = f1r - g1i; ui[3] = f1i + g1r; ur[7] = f1r + g1i; ui[7] = f1i - g1r; }
}

// Wave-local 512-pt complex FFT, Stockham radix-8, 3 stages, single LDS buffer.
// Twiddles come from per-lane REGISTER tables (t2*, t3*), not LDS.
// slot m of lane t <-> element (t + 64*m), natural order both sides. No barriers.
template<int SGN>
__device__ __forceinline__ void fft512w(float* ur, float* ui,
                                        float2* __restrict__ buf,
                                        const float* t2c, const float* t2s,
                                        const float* t3c, const float* t3s,
                                        int t) {
    bfly8<SGN>(ur, ui);
    LDSFENCE();
#pragma unroll
    for (int m = 0; m < 8; ++m) buf[SWZ(8 * t + m)] = make_float2(ur[m], ui[m]);
    LDSFENCE();
#pragma unroll
    for (int m = 0; m < 8; ++m) { const float2 v = buf[SWZ(t + 64 * m)]; ur[m] = v.x; ui[m] = v.y; }
#pragma unroll
    for (int m = 1; m < 8; ++m) twmul<SGN>(ur[m], ui[m], t2c[m], t2s[m]);
    bfly8<SGN>(ur, ui);
    const int k2 = t & 7;
    const int jj = ((t >> 3) << 6) + k2;
    LDSFENCE();
#pragma unroll
    for (int m = 0; m < 8; ++m) buf[SWZ(jj + 8 * m)] = make_float2(ur[m], ui[m]);
    LDSFENCE();
#pragma unroll
    for (int m = 0; m < 8; ++m) { const float2 v = buf[SWZ(t + 64 * m)]; ur[m] = v.x; ui[m] = v.y; }
#pragma unroll
    for (int m = 1; m < 8; ++m) twmul<SGN>(ur[m], ui[m], t3c[m], t3s[m]);
    bfly8<SGN>(ur, ui);
    LDSFENCE();
}

__global__ __launch_bounds__(256, 2) void pbfd_kernel(
    const float* __restrict__ g_mic,   // (B,256)
    const float* __restrict__ g_lsb,   // (B,1280)
    const float* __restrict__ g_phie,  // (B,257)
    const float* __restrict__ g_p1,    // (B,257,4)
    const float* __restrict__ g_hr,    // (B,257,4)
    const float* __restrict__ g_hi,    // (B,257,4)
    float* __restrict__ g_out,         // (B,256)
    int B) {
    __shared__ float2 xch[4][512];     // one exchange buffer per wave (no shared tables)

    const int tid = threadIdx.x;
    const int w = tid >> 6;
    const int t = tid & 63;
    const int elem = blockIdx.x * 4 + w;
    if (elem >= B) return;  // no barriers anywhere: early-exit is safe
    float2* buf = &xch[w][0];
    const int ml = (64 - t) & 63;  // mirror lane: bin 512-k lives at (ml, 7-m) for t>=1

    // ---- per-lane register twiddle tables (constant across all 9 FFTs) ----
    // t2[m] = e^{+2pi i m (t&7)/64}, t3[m] = e^{+2pi i m t/512}, m=1..7
    float t2c[8], t2s[8], t3c[8], t3s[8];
    {
        float s2, c2, s3, c3;
        sincosf(PI2 * (float)(t & 7) * (1.0f / 64.0f), &s2, &c2);
        sincosf(PI2 * (float)t * (1.0f / 512.0f), &s3, &c3);
        t2c[0] = 1.f; t2s[0] = 0.f; t3c[0] = 1.f; t3s[0] = 0.f;
        t2c[1] = c2; t2s[1] = s2; t3c[1] = c3; t3s[1] = s3;
#pragma unroll
        for (int m = 2; m < 8; ++m) {
            const float pc2 = t2c[m - 1], ps2 = t2s[m - 1];
            t2c[m] = pc2 * c2 - ps2 * s2;
            t2s[m] = ps2 * c2 + pc2 * s2;
            const float pc3 = t3c[m - 1], ps3 = t3s[m - 1];
            t3c[m] = pc3 * c3 - ps3 * s3;
            t3s[m] = ps3 * c3 + pc3 * s3;
        }
    }

    float mv[4];
    {
        const float* mp = g_mic + (size_t)elem * 256;
#pragma unroll
        for (int q = 0; q < 4; ++q) mv[q] = mp[t + 64 * q];
    }

    // ---- X: 4 real frame-FFTs as 2 paired complex FFTs; keep low bins + lane0 Nyquist ----
    float xr[4][4], xi[4][4], xn[4];
    {
        const float* lb = g_lsb + (size_t)elem * 1280;
#pragma unroll
        for (int pr = 0; pr < 2; ++pr) {
            float ur[8], ui[8];
#pragma unroll
            for (int m = 0; m < 8; ++m) {
                ur[m] = lb[(2 * pr) * 256 + t + 64 * m];
                ui[m] = lb[(2 * pr + 1) * 256 + t + 64 * m];
            }
            fft512w<-1>(ur, ui, buf, t2c, t2s, t3c, t3s, t);
#pragma unroll
            for (int m = 0; m < 4; ++m) {
                float zmr = __shfl(ur[7 - m], ml);
                float zmi = __shfl(ui[7 - m], ml);
                if (t == 0) {  // lane0: mirror of bin 64m is slot 8-m (self for m=0)
                    zmr = (m == 0) ? ur[0] : ur[8 - m];
                    zmi = (m == 0) ? ui[0] : ui[8 - m];
                }
                xr[2 * pr][m]     = 0.5f * (ur[m] + zmr);
                xi[2 * pr][m]     = 0.5f * (ui[m] - zmi);
                xr[2 * pr + 1][m] = 0.5f * (ui[m] + zmi);
                xi[2 * pr + 1][m] = -0.5f * (ur[m] - zmr);
            }
            if (t == 0) { xn[2 * pr] = ur[4]; xn[2 * pr + 1] = ui[4]; }  // X[256] re/im-packed
        }
    }

    // ---- H (low bins; lane0: real part of H[256] — its imag is dead for the output) ----
    float hr_[4][4], hi_[4][4], hn[4];
    {
        const float4* hr4 = (const float4*)g_hr + (size_t)elem * 257;
        const float4* hi4 = (const float4*)g_hi + (size_t)elem * 257;
#pragma unroll
        for (int m = 0; m < 4; ++m) {
            const float4 a = hr4[t + 64 * m];
            hr_[0][m] = a.x; hr_[1][m] = a.y; hr_[2][m] = a.z; hr_[3][m] = a.w;
        }
#pragma unroll
        for (int m = 0; m < 4; ++m) {
            const float4 b = hi4[t + 64 * m];
            hi_[0][m] = b.x; hi_[1][m] = b.y; hi_[2][m] = b.z; hi_[3][m] = b.w;
        }
    }
    float pn[4] = {0, 0, 0, 0};
    if (t == 0) {
        const float4* hr4 = (const float4*)g_hr + (size_t)elem * 257;
        const float4* p14 = (const float4*)g_p1 + (size_t)elem * 257;
        const float4 a = hr4[256], p = p14[256];
        hn[0] = a.x; hn[1] = a.y; hn[2] = a.z; hn[3] = a.w;
        pn[0] = p.x; pn[1] = p.y; pn[2] = p.z; pn[3] = p.w;
    }

    // C = sum_j X*H at low slots; Hermitian high-half reconstruction; IFFT; o4 = Re(out)[4..7]/512
    auto sum_ifft = [&](float o4[4]) {
        float ur[8], ui[8];
#pragma unroll
        for (int m = 0; m < 4; ++m) {
            float cr = 0.f, ci = 0.f;
#pragma unroll
            for (int j = 0; j < 4; ++j) {
                cr += xr[j][m] * hr_[j][m] - xi[j][m] * hi_[j][m];
                ci += xr[j][m] * hi_[j][m] + xi[j][m] * hr_[j][m];
            }
            ur[m] = cr; ui[m] = ci;
        }
#pragma unroll
        for (int m = 4; m < 8; ++m) {  // high slot = conj(mirror-lane low slot 7-m)
            const float cr = __shfl(ur[7 - m], ml);
            const float ci = __shfl(ui[7 - m], ml);
            ur[m] = cr; ui[m] = -ci;
        }
        if (t == 0) {
            ur[5] = ur[3]; ui[5] = -ui[3];
            ur[6] = ur[2]; ui[6] = -ui[2];
            ur[7] = ur[1]; ui[7] = -ui[1];
            float cn = 0.f;
#pragma unroll
            for (int j = 0; j < 4; ++j) cn += xn[j] * hn[j];
            ur[4] = cn; ui[4] = 0.f;  // Nyquist: real
        }
        fft512w<1>(ur, ui, buf, t2c, t2s, t3c, t3s, t);
#pragma unroll
        for (int q = 0; q < 4; ++q) o4[q] = ur[4 + q] * (1.0f / 512.0f);
    };

    // ---- est (H prior), d = mic - est ----
    float d4[4];
    {
        float o4[4];
        sum_ifft(o4);
#pragma unroll
        for (int q = 0; q < 4; ++q) d4[q] = mv[q] - o4[q];
    }

    // ---- E = FFT([zeros(256); d]) ----
    float er[4], ei[4], en = 0.f;
    {
        float ur[8], ui[8];
#pragma unroll
        for (int m = 0; m < 4; ++m) { ur[m] = 0.f; ui[m] = 0.f; }
#pragma unroll
        for (int q = 0; q < 4; ++q) { ur[4 + q] = d4[q]; ui[4 + q] = 0.f; }
        fft512w<-1>(ur, ui, buf, t2c, t2s, t3c, t3s, t);
#pragma unroll
        for (int m = 0; m < 4; ++m) { er[m] = ur[m]; ei[m] = ui[m]; }
        if (t == 0) en = ur[4];
    }

    // ---- phi_e ----
    float pe[4], pen = 0.f;
    {
        const float* php = g_phie + (size_t)elem * 257;
#pragma unroll
        for (int m = 0; m < 4; ++m)
            pe[m] = 0.7f * php[t + 64 * m] + 0.3f * (er[m] * er[m] + ei[m] * ei[m]);
        if (t == 0) pen = 0.7f * php[256] + 0.3f * en * en;
    }

    // ---- gradient: partitions paired (0,1), (2,3): IFFT(KE0 + i*KE1) -> mask -> FFT -> unpack ----
    {
        const float4* p14 = (const float4*)g_p1 + (size_t)elem * 257;
#pragma unroll
        for (int pr = 0; pr < 2; ++pr) {
            const int j0 = 2 * pr, j1 = 2 * pr + 1;
            float ur[8], ui[8], gr[4], gi[4];
#pragma unroll
            for (int m = 0; m < 4; ++m) {
                // KE_j = P1_j * conj(X_j) / R_j * E  (P1 reloaded here, cache-hot)
                const float4 p = p14[t + 64 * m];
                const float pa = pr ? p.z : p.x;
                const float pb = pr ? p.w : p.y;
                const float xxa = xr[j0][m] * xr[j0][m] + xi[j0][m] * xi[j0][m];
                const float Ra = xxa * pa + 2.f * pe[m] + 1e-10f;
                const float ia = 1.f / Ra;
                const float kra = pa * xr[j0][m] * ia, kia = -pa * xi[j0][m] * ia;
                const float a_r = kra * er[m] - kia * ei[m];
                const float a_i = kra * ei[m] + kia * er[m];
                const float xxb = xr[j1][m] * xr[j1][m] + xi[j1][m] * xi[j1][m];
                const float Rb = xxb * pb + 2.f * pe[m] + 1e-10f;
                const float ib = 1.f / Rb;
                const float krb = pb * xr[j1][m] * ib, kib = -pb * xi[j1][m] * ib;
                const float b_r = krb * er[m] - kib * ei[m];
                const float b_i = krb * ei[m] + kib * er[m];
                ur[m] = a_r - b_i;  ui[m] = a_i + b_r;   // KE0 + i*KE1
                gr[m] = a_r + b_i;  gi[m] = b_r - a_i;   // conj-pack for mirror lanes
            }
#pragma unroll
            for (int m = 4; m < 8; ++m) {
                ur[m] = __shfl(gr[7 - m], ml);
                ui[m] = __shfl(gi[7 - m], ml);
            }
            if (t == 0) {
                ur[5] = gr[3]; ui[5] = gi[3];
                ur[6] = gr[2]; ui[6] = gi[2];
                ur[7] = gr[1]; ui[7] = gi[1];
                const float Rn0 = xn[j0] * xn[j0] * pn[j0] + 2.f * pen + 1e-10f;
                const float Rn1 = xn[j1] * xn[j1] * pn[j1] + 2.f * pen + 1e-10f;
                ur[4] = pn[j0] * xn[j0] / Rn0 * en;   // KE0[256] (real)
                ui[4] = pn[j1] * xn[j1] / Rn1 * en;   // KE1[256] (real)
            }
            fft512w<1>(ur, ui, buf, t2c, t2s, t3c, t3s, t);  // -> 512*(dH0 + i*dH1)
            // mask n<256 (slots m<4), scale 1/512, FFT the still-packed pair
#pragma unroll
            for (int m = 0; m < 4; ++m) { ur[m] *= (1.0f / 512.0f); ui[m] *= (1.0f / 512.0f); }
#pragma unroll
            for (int m = 4; m < 8; ++m) { ur[m] = 0.f; ui[m] = 0.f; }
            fft512w<-1>(ur, ui, buf, t2c, t2s, t3c, t3s, t);  // Z = fd_dH0 + i*fd_dH1
            // unpack at low slots: fd0 = (Z + conj(Zm))/2, fd1 = -i/2 (Z - conj(Zm))
#pragma unroll
            for (int m = 0; m < 4; ++m) {
                float zmr = __shfl(ur[7 - m], ml);
                float zmi = __shfl(ui[7 - m], ml);
                if (t == 0) {
                    zmr = (m == 0) ? ur[0] : ur[8 - m];
                    zmi = (m == 0) ? ui[0] : ui[8 - m];
                }
                const float f0r = 0.5f * (ur[m] + zmr), f0i = 0.5f * (ui[m] - zmi);
                const float f1r = 0.5f * (ui[m] + zmi), f1i = -0.5f * (ur[m] - zmr);
                hr_[j0][m] = SF * (hr_[j0][m] + f0r);
                hi_[j0][m] = SF * (hi_[j0][m] + f0i);
                hr_[j1][m] = SF * (hr_[j1][m] + f1r);
                hi_[j1][m] = SF * (hi_[j1][m] + f1i);
            }
            if (t == 0) {
                hn[j0] = SF * (hn[j0] + ur[4]);  // fd_dH0[256] = Re(Z4)
                hn[j1] = SF * (hn[j1] + ui[4]);  // fd_dH1[256] = Im(Z4)
            }
        }
    }

    // ---- enhanced = mic - Re(IFFT(sum X*H_new))[256:] ----
    {
        float o4[4];
        sum_ifft(o4);
        float* op = g_out + (size_t)elem * 256;
#pragma unroll
        for (int q = 0; q < 4; ++q) op[t + 64 * q] = mv[q] - o4[q];
    }
}

extern "C" void kernel_launch(void* const* d_in, const int* in_sizes, int n_in,
                              void* d_out, int out_size, void* d_ws, size_t ws_size,
                              hipStream_t stream) {
    const float* mic  = (const float*)d_in[0];
    const float* lsb  = (const float*)d_in[1];
    const float* phie = (const float*)d_in[2];
    // d_in[3] = phi_f: dead for the 'enhanced' output
    const float* p1   = (const float*)d_in[4];
    const float* hr   = (const float*)d_in[5];
    const float* hi   = (const float*)d_in[6];
    float* out = (float*)d_out;

    const int B = in_sizes[0] / 256;  // N_MIC == 1
    const int blocks = (B + 3) / 4;   // 4 elements (waves) per 256-thread block
    pbfd_kernel<<<blocks, 256, 0, stream>>>(mic, lsb, phie, p1, hr, hi, out, B);
}

// Round 9
// 36.761 us; speedup vs baseline: 1.6209x; 1.3682x over previous
//
#include <hip/hip_runtime.h>
#include <math.h>

#define SF 0.99999f
#define PI2 6.283185307179586476925f
#define SWZ(c) ((c) ^ (((c) >> 4) & 15))
// compiler-only fence: orders same-wave LDS write/read phases (HW LDS pipe is
// in-order per wave; this stops compiler reordering).
#define LDSFENCE() asm volatile("" ::: "memory")

template<int SGN>
__device__ __forceinline__ void twmul(float& ur, float& ui, float c, float s) {
    const float ss = (SGN < 0) ? -s : s;
    const float r = ur * c - ui * ss;
    const float i = ui * c + ur * ss;
    ur = r; ui = i;
}

// 8-point DFT across registers. SGN=-1: forward; SGN=+1: inverse.
template<int SGN>
__device__ __forceinline__ void bfly8(float* ur, float* ui) {
    const float C2 = 0.70710678118654752440f;
    float ar[4], ai[4], br[4], bi[4];
#pragma unroll
    for (int m = 0; m < 4; ++m) {
        ar[m] = ur[m] + ur[m + 4]; ai[m] = ui[m] + ui[m + 4];
        br[m] = ur[m] - ur[m + 4]; bi[m] = ui[m] - ui[m + 4];
    }
    float b1r, b1i, b2r, b2i, b3r, b3i;
    if (SGN < 0) {
        b1r = C2 * (br[1] + bi[1]); b1i = C2 * (bi[1] - br[1]);
        b2r = bi[2];                b2i = -br[2];
        b3r = C2 * (bi[3] - br[3]); b3i = -C2 * (br[3] + bi[3]);
    } else {
        b1r = C2 * (br[1] - bi[1]); b1i = C2 * (bi[1] + br[1]);
        b2r = -bi[2];               b2i = br[2];
        b3r = -C2 * (br[3] + bi[3]); b3i = C2 * (br[3] - bi[3]);
    }
    const float e0r = ar[0] + ar[2], e0i = ai[0] + ai[2];
    const float e1r = ar[0] - ar[2], e1i = ai[0] - ai[2];
    const float o0r = ar[1] + ar[3], o0i = ai[1] + ai[3];
    const float o1r = ar[1] - ar[3], o1i = ai[1] - ai[3];
    ur[0] = e0r + o0r; ui[0] = e0i + o0i;
    ur[4] = e0r - o0r; ui[4] = e0i - o0i;
    if (SGN < 0) { ur[2] = e1r + o1i; ui[2] = e1i - o1r; ur[6] = e1r - o1i; ui[6] = e1i + o1r; }
    else         { ur[2] = e1r - o1i; ui[2] = e1i + o1r; ur[6] = e1r + o1i; ui[6] = e1i - o1r; }
    const float f0r = br[0] + b2r, f0i = bi[0] + b2i;
    const float f1r = br[0] - b2r, f1i = bi[0] - b2i;
    const float g0r = b1r + b3r, g0i = b1i + b3i;
    const float g1r = b1r - b3r, g1i = b1i - b3i;
    ur[1] = f0r + g0r; ui[1] = f0i + g0i;
    ur[5] = f0r - g0r; ui[5] = f0i - g0i;
    if (SGN < 0) { ur[3] = f1r + g1i; ui[3] = f1i - g1r; ur[7] = f1r - g1i; ui[7] = f1i + g1r; }
    else         { ur[3] = f1r - g1i; ui[3] = f1i + g1r; ur[7] = f1r + g1i; ui[7] = f1i - g1r; }
}

// Wave-local 512-pt complex FFT, Stockham radix-8, 3 stages, single LDS buffer.
// ra[8] = hoisted read indices SWZ(t+64m) (used by both read phases).
// Writes use per-element inline SWZ (no contiguity assumption). No barriers.
template<int SGN>
__device__ __forceinline__ void fft512w(float* ur, float* ui,
                                        float2* __restrict__ buf,
                                        const float2* __restrict__ tw2,
                                        const float2* __restrict__ tw3,
                                        const int* ra, int t) {
    bfly8<SGN>(ur, ui);
    LDSFENCE();
#pragma unroll
    for (int m = 0; m < 8; ++m) buf[SWZ(8 * t + m)] = make_float2(ur[m], ui[m]);
    LDSFENCE();
#pragma unroll
    for (int m = 0; m < 8; ++m) { const float2 v = buf[ra[m]]; ur[m] = v.x; ui[m] = v.y; }
    const int k2 = t & 7;
#pragma unroll
    for (int m = 1; m < 8; ++m) { const float2 w = tw2[m * 8 + k2]; twmul<SGN>(ur[m], ui[m], w.x, w.y); }
    bfly8<SGN>(ur, ui);
    const int jj = ((t >> 3) << 6) + k2;
    LDSFENCE();
#pragma unroll
    for (int m = 0; m < 8; ++m) buf[SWZ(jj + 8 * m)] = make_float2(ur[m], ui[m]);
    LDSFENCE();
#pragma unroll
    for (int m = 0; m < 8; ++m) { const float2 v = buf[ra[m]]; ur[m] = v.x; ui[m] = v.y; }
#pragma unroll
    for (int m = 1; m < 8; ++m) { const float2 w = tw3[m * 64 + t]; twmul<SGN>(ur[m], ui[m], w.x, w.y); }
    bfly8<SGN>(ur, ui);
    LDSFENCE();
}

__global__ __launch_bounds__(256, 2) void pbfd_kernel(
    const float* __restrict__ g_mic,   // (B,256)
    const float* __restrict__ g_lsb,   // (B,1280)
    const float* __restrict__ g_phie,  // (B,257)
    const float* __restrict__ g_p1,    // (B,257,4)
    const float* __restrict__ g_hr,    // (B,257,4)
    const float* __restrict__ g_hi,    // (B,257,4)
    float* __restrict__ g_out,         // (B,256)
    int B) {
    __shared__ float2 tw2[64];
    __shared__ float2 tw3[512];
    __shared__ float2 xch[4][512];     // one exchange buffer per wave

    const int tid = threadIdx.x;
    for (int e = tid; e < 512; e += 256) {
        const int m = e >> 6, tt = e & 63;
        float s, c;
        sincosf(PI2 * (float)(m * tt) * (1.0f / 512.0f), &s, &c);
        tw3[e] = make_float2(c, s);
    }
    if (tid < 64) {
        const int m = tid >> 3, k = tid & 7;
        float s, c;
        sincosf(PI2 * (float)(m * k) * (1.0f / 64.0f), &s, &c);
        tw2[tid] = make_float2(c, s);
    }
    __syncthreads();  // the only barrier

    const int w = tid >> 6;
    const int t = tid & 63;
    const int elem = blockIdx.x * 4 + w;
    if (elem >= B) return;
    float2* buf = &xch[w][0];
    const int ml = (64 - t) & 63;  // mirror lane: bin 512-k lives at (ml, 7-m) for t>=1

    // ---- hoisted LDS read indices (invariant across all 9 FFTs) ----
    int ra[8];
#pragma unroll
    for (int m = 0; m < 8; ++m) ra[m] = SWZ(t + 64 * m);

    float mv[4];
    {
        const float* mp = g_mic + (size_t)elem * 256;
#pragma unroll
        for (int q = 0; q < 4; ++q) mv[q] = mp[t + 64 * q];
    }

    // ---- X: 4 real frame-FFTs as 2 paired complex FFTs; keep low bins + lane0 Nyquist ----
    float xr[4][4], xi[4][4], xn[4];
    {
        const float* lb = g_lsb + (size_t)elem * 1280;
#pragma unroll
        for (int pr = 0; pr < 2; ++pr) {
            float ur[8], ui[8];
#pragma unroll
            for (int m = 0; m < 8; ++m) {
                ur[m] = lb[(2 * pr) * 256 + t + 64 * m];
                ui[m] = lb[(2 * pr + 1) * 256 + t + 64 * m];
            }
            fft512w<-1>(ur, ui, buf, tw2, tw3, ra, t);
#pragma unroll
            for (int m = 0; m < 4; ++m) {
                float zmr = __shfl(ur[7 - m], ml);
                float zmi = __shfl(ui[7 - m], ml);
                if (t == 0) {  // lane0: mirror of bin 64m is slot 8-m (self for m=0)
                    zmr = (m == 0) ? ur[0] : ur[8 - m];
                    zmi = (m == 0) ? ui[0] : ui[8 - m];
                }
                xr[2 * pr][m]     = 0.5f * (ur[m] + zmr);
                xi[2 * pr][m]     = 0.5f * (ui[m] - zmi);
                xr[2 * pr + 1][m] = 0.5f * (ui[m] + zmi);
                xi[2 * pr + 1][m] = -0.5f * (ur[m] - zmr);
            }
            if (t == 0) { xn[2 * pr] = ur[4]; xn[2 * pr + 1] = ui[4]; }  // X[256] re/im-packed
        }
    }

    // Hermitian IFFT of a low-half spectrum (cr/ci low slots + lane0 Nyquist cn):
    // o4[q] = Re(ifft)[256+t+64q]/512. (DC/Nyq imag residue only pollutes the
    // discarded imaginary part -> matches numpy irfft semantics.)
    auto herm_ifft = [&](const float cr[4], const float ci[4], float cn, float o4[4]) {
        float ur[8], ui[8];
#pragma unroll
        for (int m = 0; m < 4; ++m) { ur[m] = cr[m]; ui[m] = ci[m]; }
#pragma unroll
        for (int m = 4; m < 8; ++m) {  // high slot = conj(mirror-lane low slot 7-m)
            ur[m] = __shfl(cr[7 - m], ml);
            ui[m] = -__shfl(ci[7 - m], ml);
        }
        if (t == 0) {
            ur[5] = cr[3]; ui[5] = -ci[3];
            ur[6] = cr[2]; ui[6] = -ci[2];
            ur[7] = cr[1]; ui[7] = -ci[1];
            ur[4] = cn; ui[4] = 0.f;  // Nyquist: real
        }
        fft512w<1>(ur, ui, buf, tw2, tw3, ra, t);
#pragma unroll
        for (int q = 0; q < 4; ++q) o4[q] = ur[4 + q] * (1.0f / 512.0f);
    };

    // ---- est (H prior): C = sum_j X*H; d = mic - est.  H dies after this block. ----
    float d4[4];
    float pn[4], en = 0.f, pen = 0.f;  // lane0 side channel
    {
        float hr_[4][4], hi_[4][4], hn[4];
        {
            const float4* hr4 = (const float4*)g_hr + (size_t)elem * 257;
            const float4* hi4 = (const float4*)g_hi + (size_t)elem * 257;
#pragma unroll
            for (int m = 0; m < 4; ++m) {
                const float4 a = hr4[t + 64 * m];
                hr_[0][m] = a.x; hr_[1][m] = a.y; hr_[2][m] = a.z; hr_[3][m] = a.w;
            }
#pragma unroll
            for (int m = 0; m < 4; ++m) {
                const float4 b = hi4[t + 64 * m];
                hi_[0][m] = b.x; hi_[1][m] = b.y; hi_[2][m] = b.z; hi_[3][m] = b.w;
            }
            if (t == 0) {
                const float4 a = hr4[256];
                const float4 p = ((const float4*)g_p1)[(size_t)elem * 257 + 256];
                hn[0] = a.x; hn[1] = a.y; hn[2] = a.z; hn[3] = a.w;
                pn[0] = p.x; pn[1] = p.y; pn[2] = p.z; pn[3] = p.w;
            }
        }
        float cr[4], ci[4], cn = 0.f;
#pragma unroll
        for (int m = 0; m < 4; ++m) {
            float sr = 0.f, si = 0.f;
#pragma unroll
            for (int j = 0; j < 4; ++j) {
                sr += xr[j][m] * hr_[j][m] - xi[j][m] * hi_[j][m];
                si += xr[j][m] * hi_[j][m] + xi[j][m] * hr_[j][m];
            }
            cr[m] = sr; ci[m] = si;
        }
        if (t == 0) {
#pragma unroll
            for (int j = 0; j < 4; ++j) cn += xn[j] * hn[j];
        }
        float o4[4];
        herm_ifft(cr, ci, cn, o4);
#pragma unroll
        for (int q = 0; q < 4; ++q) d4[q] = mv[q] - o4[q];
    }

    // ---- E = FFT([zeros(256); d]) ----
    float er[4], ei[4];
    {
        float ur[8], ui[8];
#pragma unroll
        for (int m = 0; m < 4; ++m) { ur[m] = 0.f; ui[m] = 0.f; }
#pragma unroll
        for (int q = 0; q < 4; ++q) { ur[4 + q] = d4[q]; ui[4 + q] = 0.f; }
        fft512w<-1>(ur, ui, buf, tw2, tw3, ra, t);
#pragma unroll
        for (int m = 0; m < 4; ++m) { er[m] = ur[m]; ei[m] = ui[m]; }
        if (t == 0) en = ur[4];
    }

    // ---- phi_e ----
    float pe[4];
    {
        const float* php = g_phie + (size_t)elem * 257;
#pragma unroll
        for (int m = 0; m < 4; ++m)
            pe[m] = 0.7f * php[t + 64 * m] + 0.3f * (er[m] * er[m] + ei[m] * ei[m]);
        if (t == 0) pen = 0.7f * php[256] + 0.3f * en * en;
    }

    // ---- gradient: pairs (0,1),(2,3): IFFT(KE0+i*KE1) -> mask -> FFT ->
    //      unpack fd_dH and accumulate D = sum_j X_j * fd_dH_j on the fly ----
    float Dr[4] = {0, 0, 0, 0}, Di[4] = {0, 0, 0, 0};
    float dn = 0.f;  // lane0: D at Nyquist
    {
        const float4* p14 = (const float4*)g_p1 + (size_t)elem * 257;
#pragma unroll
        for (int pr = 0; pr < 2; ++pr) {
            const int j0 = 2 * pr, j1 = 2 * pr + 1;
            float ur[8], ui[8], gr[4], gi[4];
#pragma unroll
            for (int m = 0; m < 4; ++m) {
                // KE_j = P1_j * conj(X_j) / R_j * E  (P1 reloaded here, cache-hot)
                const float4 p = p14[t + 64 * m];
                const float pa = pr ? p.z : p.x;
                const float pb = pr ? p.w : p.y;
                const float xxa = xr[j0][m] * xr[j0][m] + xi[j0][m] * xi[j0][m];
                const float Ra = xxa * pa + 2.f * pe[m] + 1e-10f;
                const float ia = 1.f / Ra;
                const float kra = pa * xr[j0][m] * ia, kia = -pa * xi[j0][m] * ia;
                const float a_r = kra * er[m] - kia * ei[m];
                const float a_i = kra * ei[m] + kia * er[m];
                const float xxb = xr[j1][m] * xr[j1][m] + xi[j1][m] * xi[j1][m];
                const float Rb = xxb * pb + 2.f * pe[m] + 1e-10f;
                const float ib = 1.f / Rb;
                const float krb = pb * xr[j1][m] * ib, kib = -pb * xi[j1][m] * ib;
                const float b_r = krb * er[m] - kib * ei[m];
                const float b_i = krb * ei[m] + kib * er[m];
                ur[m] = a_r - b_i;  ui[m] = a_i + b_r;   // KE0 + i*KE1
                gr[m] = a_r + b_i;  gi[m] = b_r - a_i;   // conj-pack for mirror lanes
            }
#pragma unroll
            for (int m = 4; m < 8; ++m) {
                ur[m] = __shfl(gr[7 - m], ml);
                ui[m] = __shfl(gi[7 - m], ml);
            }
            if (t == 0) {
                ur[5] = gr[3]; ui[5] = gi[3];
                ur[6] = gr[2]; ui[6] = gi[2];
                ur[7] = gr[1]; ui[7] = gi[1];
                const float Rn0 = xn[j0] * xn[j0] * pn[j0] + 2.f * pen + 1e-10f;
                const float Rn1 = xn[j1] * xn[j1] * pn[j1] + 2.f * pen + 1e-10f;
                ur[4] = pn[j0] * xn[j0] / Rn0 * en;   // KE0[256] (real)
                ui[4] = pn[j1] * xn[j1] / Rn1 * en;   // KE1[256] (real)
            }
            fft512w<1>(ur, ui, buf, tw2, tw3, ra, t);  // -> 512*(dH0 + i*dH1)
            // mask n<256 (slots m<4), scale 1/512, FFT the still-packed pair
#pragma unroll
            for (int m = 0; m < 4; ++m) { ur[m] *= (1.0f / 512.0f); ui[m] *= (1.0f / 512.0f); }
#pragma unroll
            for (int m = 4; m < 8; ++m) { ur[m] = 0.f; ui[m] = 0.f; }
            fft512w<-1>(ur, ui, buf, tw2, tw3, ra, t);  // Z = fd_dH0 + i*fd_dH1
            // unpack at low slots: fd0 = (Z + conj(Zm))/2, fd1 = -i/2 (Z - conj(Zm));
            // accumulate D += X_j0*fd0 + X_j1*fd1
#pragma unroll
            for (int m = 0; m < 4; ++m) {
                float zmr = __shfl(ur[7 - m], ml);
                float zmi = __shfl(ui[7 - m], ml);
                if (t == 0) {
                    zmr = (m == 0) ? ur[0] : ur[8 - m];
                    zmi = (m == 0) ? ui[0] : ui[8 - m];
                }
                const float f0r = 0.5f * (ur[m] + zmr), f0i = 0.5f * (ui[m] - zmi);
                const float f1r = 0.5f * (ui[m] + zmi), f1i = -0.5f * (ur[m] - zmr);
                Dr[m] += xr[j0][m] * f0r - xi[j0][m] * f0i + xr[j1][m] * f1r - xi[j1][m] * f1i;
                Di[m] += xr[j0][m] * f0i + xi[j0][m] * f0r + xr[j1][m] * f1i + xi[j1][m] * f1r;
            }
            if (t == 0) dn += xn[j0] * ur[4] + xn[j1] * ui[4];  // fd_dH nyq: Re/Im of Z4
        }
    }

    // ---- enhanced = mic - SF*(est + irfft(D)[256:]) ;  est = mic - d ----
    {
        float o4[4];
        herm_ifft(Dr, Di, dn, o4);
        float* op = g_out + (size_t)elem * 256;
#pragma unroll
        for (int q = 0; q < 4; ++q)
            op[t + 64 * q] = mv[q] - SF * ((mv[q] - d4[q]) + o4[q]);
    }
}

extern "C" void kernel_launch(void* const* d_in, const int* in_sizes, int n_in,
                              void* d_out, int out_size, void* d_ws, size_t ws_size,
                              hipStream_t stream) {
    const float* mic  = (const float*)d_in[0];
    const float* lsb  = (const float*)d_in[1];
    const float* phie = (const float*)d_in[2];
    // d_in[3] = phi_f: dead for the 'enhanced' output
    const float* p1   = (const float*)d_in[4];
    const float* hr   = (const float*)d_in[5];
    const float* hi   = (const float*)d_in[6];
    float* out = (float*)d_out;

    const int B = in_sizes[0] / 256;  // N_MIC == 1
    const int blocks = (B + 3) / 4;   // 4 elements (waves) per 256-thread block
    pbfd_kernel<<<blocks, 256, 0, stream>>>(mic, lsb, phie, p1, hr, hi, out, B);
}